// Round 7
// baseline (614.085 us; speedup 1.0000x reference)
//
#include <hip/hip_runtime.h>
#include <float.h>

typedef unsigned short u16;
typedef unsigned int u32;

// B=2, N=8192, M=4096, C=64, K=16, HID=256
__device__ __forceinline__ float bf(u16 u) { return __uint_as_float(((u32)u) << 16); }
__device__ __forceinline__ u16 f2bf(float v) {
    u32 x = __float_as_uint(v);
    u32 r = x + 0x7fffu + ((x >> 16) & 1u);
    return (u16)(r >> 16);
}
// Dtype probe on EVEN u16 positions of a large ~N(0,1) buffer (pcl_noise):
//  bf16 data: even u16s are bf16 values -> exponent field in [100,140] essentially always.
//  fp32 data: even u16s are low-mantissa bits -> exponent field ~uniform (~16% in band).
__device__ __forceinline__ int detect_f32(const void* probe) {
    const u16* u = (const u16*)probe;
    u16 v = u[(threadIdx.x & 63) * 2];
    int e = (int)((v >> 7) & 0xFF);
    int moderate = (e >= 100) && (e <= 140);
    return __popcll(__ballot(moderate)) < 48;   // few moderate -> fp32
}
__device__ __forceinline__ float ldv(int f32, const void* p, int i) {
    return f32 ? ((const float*)p)[i] : bf(((const u16*)p)[i]);
}
// fma-chain dot (BLAS/XLA-like); on bf16-valued data identical to mul/add chain.
__device__ __forceinline__ float dot3(float x0, float x1, float x2,
                                      float y0, float y1, float y2) {
    return __fmaf_rn(x2, y2, __fmaf_rn(x1, y1, __fmul_rn(x0, y0)));
}

// ---- canon: w2b | w1a | w1b as FP32 table (dtype-normalized, full precision) ----
__global__ __launch_bounds__(256) void k_canon(const void* __restrict__ probe,
                                               const void* __restrict__ w2b,
                                               const void* __restrict__ w1a,
                                               const void* __restrict__ w1b,
                                               float* __restrict__ canon) {
    int f32 = detect_f32(probe);
    int ix = blockIdx.x * 256 + threadIdx.x;       // 0..32767
    const void* src; int j;
    if (ix < 16384)      { src = w2b; j = ix; }          // 64x256
    else if (ix < 28672) { src = w1a; j = ix - 16384; }  // 64x192
    else                 { src = w1b; j = ix - 28672; }  // 64x64
    canon[ix] = ldv(f32, src, j);
}

// ---- prep: pcl -> float4 (x,y,z,sumsq) ----
__global__ __launch_bounds__(256) void k_prep(const void* __restrict__ probe,
                                              const void* __restrict__ pcl,
                                              float4* __restrict__ pcl4) {
    int f32 = detect_f32(probe);
    int i = blockIdx.x * 256 + threadIdx.x;        // 0..8191
    float x = ldv(f32, pcl, i*3+0), y = ldv(f32, pcl, i*3+1), z = ldv(f32, pcl, i*3+2);
    float s = __fadd_rn(__fadd_rn(__fmul_rn(x,x), __fmul_rn(y,y)), __fmul_rn(z,z));
    pcl4[i] = make_float4(x, y, z, s);
}

// ---- argmin over M for each noise point; 16 lanes per query; 32 KB chunked tile ----
__global__ __launch_bounds__(256) void k_close(const float4* __restrict__ pcl4,
                                               const void* __restrict__ noise,
                                               u16* __restrict__ cidx) {
    __shared__ __align__(16) float4 tile[2048];
    int f32 = detect_f32(noise);
    int t = threadIdx.x, g = t >> 4, s = t & 15;
    int q = blockIdx.x * 16 + g;                   // global noise-point id
    int b = q >> 13;
    const float4* src = pcl4 + ((size_t)b << 12);
    float x0 = ldv(f32, noise, q*3+0), x1 = ldv(f32, noise, q*3+1), x2 = ldv(f32, noise, q*3+2);
    float sx = __fadd_rn(__fadd_rn(__fmul_rn(x0,x0), __fmul_rn(x1,x1)), __fmul_rn(x2,x2));
    float bd = FLT_MAX; int bi = 0;
    for (int ch = 0; ch < 2; ++ch) {
        __syncthreads();
#pragma unroll
        for (int i = 0; i < 8; ++i) { int ix = t + (i << 8); tile[ix] = src[(ch << 11) + ix]; }
        __syncthreads();
        for (int j = 0; j < 128; ++j) {
            int cl = (j << 4) + s;                 // lane-interleaved: conflict-free LDS
            float4 p = tile[cl];
            float dot = dot3(x0, x1, x2, p.x, p.y, p.z);
            float d = __fadd_rn(__fsub_rn(sx, __fmul_rn(2.0f, dot)), p.w);
            int c = (ch << 11) + cl;               // strictly increasing within thread
            if (d < bd) { bd = d; bi = c; }        // -> first-min on ties
        }
    }
#pragma unroll
    for (int m = 8; m >= 1; m >>= 1) {             // lexicographic (d, idx) merge
        float od = __shfl_xor(bd, m);
        int   oi = __shfl_xor(bi, m);
        if (od < bd || (od == bd && oi < bi)) { bd = od; bi = oi; }
    }
    if (s == 0) cidx[q] = (u16)(bi & 4095);        // masked: in-bounds even on garbage data
}

// ---- top-16 NN of every clean point among pcl; 16 lanes per query; 32 KB tile ----
__global__ __launch_bounds__(256) void k_knn(const float4* __restrict__ pcl4,
                                             u16* __restrict__ knn) {
    __shared__ __align__(16) float4 tile[2048];
    int t = threadIdx.x, g = t >> 4, s = t & 15;
    int q = blockIdx.x * 16 + g;                   // global clean-point id (B*M)
    int b = q >> 12;
    int qm = q & 4095;
    const float4* src = pcl4 + ((size_t)b << 12);
    float4 Q = src[qm];
    float x0 = Q.x, x1 = Q.y, x2 = Q.z, sx = Q.w;
    float kd[16]; int ki[16];
#pragma unroll
    for (int p = 0; p < 16; ++p) { kd[p] = FLT_MAX; ki[p] = 0; }
    for (int ch = 0; ch < 2; ++ch) {
        __syncthreads();
#pragma unroll
        for (int i = 0; i < 8; ++i) { int ix = t + (i << 8); tile[ix] = src[(ch << 11) + ix]; }
        __syncthreads();
        for (int j = 0; j < 128; ++j) {
            int cl = (j << 4) + s;
            float4 p = tile[cl];
            float dot = dot3(x0, x1, x2, p.x, p.y, p.z);
            float d = __fadd_rn(__fsub_rn(sx, __fmul_rn(2.0f, dot)), p.w);
            int c = (ch << 11) + cl;
            if (d < kd[15]) {                      // strict: ties keep earlier index
                kd[15] = d; ki[15] = c;
#pragma unroll
                for (int p2 = 15; p2 > 0; --p2) {
                    if (kd[p2] < kd[p2-1]) {
                        float td = kd[p2]; kd[p2] = kd[p2-1]; kd[p2-1] = td;
                        int   ti = ki[p2]; ki[p2] = ki[p2-1]; ki[p2-1] = ti;
                    }
                }
            }
        }
    }
    __syncthreads();                               // reuse tile memory for merge
    float* md = reinterpret_cast<float*>(tile);
    int*   mi = reinterpret_cast<int*>(tile) + 4096;
#pragma unroll
    for (int p = 0; p < 16; ++p) { md[t*16+p] = kd[p]; mi[t*16+p] = ki[p]; }
    __syncthreads();
    if (s == 0) {                                  // leader: 16-way merge of sorted lists
        int heads[16];
#pragma unroll
        for (int p = 0; p < 16; ++p) heads[p] = 0;
        int base = g << 4;
        size_t ob = (size_t)q << 4;
        for (int o = 0; o < 16; ++o) {
            float bd = FLT_MAX; int bi = 0; int bt = 0;
#pragma unroll
            for (int tt = 0; tt < 16; ++tt) {
                int hp = heads[tt];
                if (hp < 16) {
                    float dv = md[(base+tt)*16 + hp];
                    int   iv = mi[(base+tt)*16 + hp];
                    if (dv < bd || (dv == bd && iv < bi)) { bd = dv; bi = iv; bt = tt; }
                }
            }
#pragma unroll
            for (int tt = 0; tt < 16; ++tt) if (tt == bt) heads[tt]++;
            knn[ob + o] = (u16)(bi & 4095);        // masked
        }
    }
}

// ---- fused tail: weights, deltas, MLP_CONV2 (k-contracted), df, MLP_CONV_1d ----
// Weights in FP32: w2a/BN in LDS; w2b/w1a/w1b rows streamed from canon (L1/L2).
// Output dtype follows detected input dtype (fp32 store vs bf16 store).
__global__ __launch_bounds__(256) void k_tail(const float4* __restrict__ pcl4,
                                              const void* __restrict__ noise,
                                              const void* __restrict__ feat,
                                              const u16* __restrict__ cidx,
                                              const u16* __restrict__ knn,
                                              const void* __restrict__ w2a,
                                              const void* __restrict__ b2a,
                                              const void* __restrict__ g2a,
                                              const void* __restrict__ bt2a,
                                              const float* __restrict__ canon,
                                              const void* __restrict__ b2b,
                                              const void* __restrict__ b1a,
                                              const void* __restrict__ g1a,
                                              const void* __restrict__ bt1a,
                                              const void* __restrict__ b1b,
                                              void* __restrict__ outp) {
    __shared__ float w2at[6][256];                 // transposed: conflict-free reads
    __shared__ float sc2[256], of2[256];
    __shared__ float b2bf[64], s1[64], o1[64], b1f[64];
    __shared__ __align__(16) float hb[4][256];     // per-wave hbar = sum_k w_k * h_k
    __shared__ __align__(16) float dfs[4][192];    // per-wave df row
    __shared__ __align__(16) float h1s[4][64];
    __shared__ float dpb[4][16][6];
    __shared__ float wbuf[4][16];
    __shared__ int   jbuf[4][16];

    int f32 = detect_f32(noise);
    int t = threadIdx.x;
    {   // stage weights + fold BN (z = dot*sc + (b*sc + bt))
        float s2 = ldv(f32, g2a, t) / sqrtf(1.0f + 1e-5f);
        sc2[t] = s2;
        of2[t] = ldv(f32, b2a, t) * s2 + ldv(f32, bt2a, t);
#pragma unroll
        for (int c = 0; c < 6; ++c) w2at[c][t] = ldv(f32, w2a, t*6+c);
        if (t < 64) {
            b2bf[t] = ldv(f32, b2b, t);
            float s = ldv(f32, g1a, t) / sqrtf(1.0f + 1e-5f);
            s1[t] = s; o1[t] = ldv(f32, b1a, t) * s + ldv(f32, bt1a, t); b1f[t] = ldv(f32, b1b, t);
        }
    }
    int lane = t & 63, wv = t >> 6;
    int q = blockIdx.x * 4 + wv;                   // one wave per noise point
    int b = q >> 13;
    int pbase = (b << 12);
    int ci = ((int)cidx[q]) & 4095;
    float4 cp = pcl4[pbase + ci];
    float x0 = ldv(f32, noise, q*3+0), x1 = ldv(f32, noise, q*3+1), x2 = ldv(f32, noise, q*3+2);
    float e = 0.0f;
    if (lane >= 1 && lane < 16) {                  // lane k handles neighbor rank k (drop rank 0)
        int jk = ((int)knn[(size_t)(pbase + ci) * 16 + lane]) & 4095;
        float4 p = pcl4[pbase + jk];
        float d0 = p.x - x0, d1 = p.y - x1, d2 = p.z - x2;
        float dst = sqrtf(__fadd_rn(__fadd_rn(__fmul_rn(d0,d0), __fmul_rn(d1,d1)), __fmul_rn(d2,d2)));
        e = expf(-10.0f * dst);
        dpb[wv][lane][0] = d0; dpb[wv][lane][1] = d1; dpb[wv][lane][2] = d2;
        dpb[wv][lane][3] = cp.x; dpb[wv][lane][4] = cp.y; dpb[wv][lane][5] = cp.z;
        jbuf[wv][lane] = jk;
    }
    float es = e;
#pragma unroll
    for (int m = 32; m >= 1; m >>= 1) es += __shfl_xor(es, m);
    float den = es + 1e-7f;
    if (lane >= 1 && lane < 16) wbuf[wv][lane] = e / den;
    float wsum = es / den;                         // sum_k w_k (for b2b term)
    __syncthreads();

    // close_feat + co_feature (lane = channel)
    size_t fcb = ((size_t)(pbase + ci)) << 6;
    float cf, co = 0.0f;
    if (f32) {
        const float* ff = (const float*)feat;
        cf = ff[fcb + lane];
#pragma unroll
        for (int k = 1; k < 16; ++k)
            co += wbuf[wv][k] * ff[(((size_t)(pbase + jbuf[wv][k])) << 6) + lane];
    } else {
        const u16* fb = (const u16*)feat;
        cf = bf(fb[fcb + lane]);
#pragma unroll
        for (int k = 1; k < 16; ++k)
            co += wbuf[wv][k] * bf(fb[(((size_t)(pbase + jbuf[wv][k])) << 6) + lane]);
    }

    // layer1: hbar[ch] = sum_k w_k * relu(bn(dp·w2a[ch])); 4 channels per lane
    float wa[4][6], scr[4], ofr[4];
#pragma unroll
    for (int r = 0; r < 4; ++r) {
        int ch = lane + (r << 6);
#pragma unroll
        for (int c = 0; c < 6; ++c) wa[r][c] = w2at[c][ch];
        scr[r] = sc2[ch]; ofr[r] = of2[ch];
    }
    float hv[4] = {0.0f, 0.0f, 0.0f, 0.0f};
#pragma unroll
    for (int k = 1; k < 16; ++k) {
        float p0 = dpb[wv][k][0], p1 = dpb[wv][k][1], p2 = dpb[wv][k][2];
        float p3 = dpb[wv][k][3], p4 = dpb[wv][k][4], p5 = dpb[wv][k][5];
        float wk = wbuf[wv][k];
#pragma unroll
        for (int r = 0; r < 4; ++r) {
            float z = p0*wa[r][0] + p1*wa[r][1] + p2*wa[r][2]
                    + p3*wa[r][3] + p4*wa[r][4] + p5*wa[r][5];
            z = z * scr[r] + ofr[r];
            z = fmaxf(z, 0.0f);
            hv[r] += wk * z;
        }
    }
#pragma unroll
    for (int r = 0; r < 4; ++r) hb[wv][lane + (r << 6)] = hv[r];
    __syncthreads();

    // layer2 (k-contracted): pf[o] = b2b[o]*wsum + sum_c hbar[c]*w2b[o][c]
    float acc = b2bf[lane] * wsum;
    {
        const float4* wrow = reinterpret_cast<const float4*>(canon + (lane << 8));
        const float4* hrow = reinterpret_cast<const float4*>(&hb[wv][0]);
#pragma unroll
        for (int i = 0; i < 64; ++i) {
            float4 w = wrow[i], h = hrow[i];
            acc += w.x*h.x + w.y*h.y + w.z*h.z + w.w*h.w;
        }
    }
    dfs[wv][lane]       = cf;                      // df = [close_feat | co_feature | point_feature]
    dfs[wv][64 + lane]  = co;
    dfs[wv][128 + lane] = acc;
    __syncthreads();

    // MLP_CONV_1d layer 1: 192 -> 64, BN+ReLU (fp32 weights from canon)
    float acc1 = 0.0f;
    {
        const float4* wr = reinterpret_cast<const float4*>(canon + 16384 + lane * 192);
        const float4* dv = reinterpret_cast<const float4*>(&dfs[wv][0]);
#pragma unroll
        for (int i = 0; i < 48; ++i) {
            float4 w = wr[i], a = dv[i];
            acc1 += w.x*a.x + w.y*a.y + w.z*a.z + w.w*a.w;
        }
    }
    float z1 = acc1 * s1[lane] + o1[lane];
    z1 = fmaxf(z1, 0.0f);
    h1s[wv][lane] = z1;
    __syncthreads();

    // MLP_CONV_1d layer 2: 64 -> 64; output dtype = detected input dtype
    float a2 = b1f[lane];
    {
        const float4* wr2 = reinterpret_cast<const float4*>(canon + 28672 + (lane << 6));
        const float4* hv2 = reinterpret_cast<const float4*>(&h1s[wv][0]);
#pragma unroll
        for (int i = 0; i < 16; ++i) {
            float4 w = wr2[i], a = hv2[i];
            a2 += w.x*a.x + w.y*a.y + w.z*a.z + w.w*a.w;
        }
    }
    size_t ob = ((size_t)q << 6) + lane;
    if (f32) ((float*)outp)[ob] = a2;
    else     ((u16*)outp)[ob]   = f2bf(a2);
}

extern "C" void kernel_launch(void* const* d_in, const int* in_sizes, int n_in,
                              void* d_out, int out_size, void* d_ws, size_t ws_size,
                              hipStream_t stream) {
    const void* pcl   = d_in[0];
    const void* noise = d_in[1];
    const void* feat  = d_in[2];
    const void* w2a   = d_in[3];
    const void* b2a   = d_in[4];
    const void* g2a   = d_in[5];
    const void* bt2a  = d_in[6];
    const void* w2b   = d_in[7];
    const void* b2b   = d_in[8];
    const void* w1a   = d_in[9];
    const void* b1a   = d_in[10];
    const void* g1a   = d_in[11];
    const void* bt1a  = d_in[12];
    const void* w1b   = d_in[13];
    const void* b1b   = d_in[14];

    char* ws = (char*)d_ws;
    float4* pcl4 = (float4*)ws;                    // 128 KB: [B,M] x (x,y,z,sumsq)
    u16* cidx = (u16*)(ws + 131072);               // 32 KB: [B,N]
    u16* knn  = (u16*)(ws + 163840);               // 256 KB: [B,M,16]
    float* canon = (float*)(ws + 425984);          // 128 KB: fp32 w2b|w1a|w1b
    // total workspace: 557,056 bytes

    k_canon<<<128,  256, 0, stream>>>(noise, w2b, w1a, w1b, canon);
    k_prep <<<32,   256, 0, stream>>>(noise, pcl, pcl4);
    k_close<<<1024, 256, 0, stream>>>(pcl4, noise, cidx);
    k_knn  <<<512,  256, 0, stream>>>(pcl4, knn);
    k_tail <<<4096, 256, 0, stream>>>(pcl4, noise, feat, cidx, knn,
                                      w2a, b2a, g2a, bt2a, canon, b2b,
                                      b1a, g1a, bt1a, b1b, d_out);
}

// Round 8
// 502.918 us; speedup vs baseline: 1.2210x; 1.2210x over previous
//
#include <hip/hip_runtime.h>
#include <float.h>

typedef unsigned short u16;
typedef unsigned int u32;

// B=2, N=8192, M=4096, C=64, K=16, HID=256
__device__ __forceinline__ float bf(u16 u) { return __uint_as_float(((u32)u) << 16); }
__device__ __forceinline__ u16 f2bf(float v) {
    u32 x = __float_as_uint(v);
    u32 r = x + 0x7fffu + ((x >> 16) & 1u);
    return (u16)(r >> 16);
}
// Dtype probe on EVEN u16 positions of a large ~N(0,1) buffer (pcl_noise).
__device__ __forceinline__ int detect_f32(const void* probe) {
    const u16* u = (const u16*)probe;
    u16 v = u[(threadIdx.x & 63) * 2];
    int e = (int)((v >> 7) & 0xFF);
    int moderate = (e >= 100) && (e <= 140);
    return __popcll(__ballot(moderate)) < 48;   // few moderate -> fp32
}
__device__ __forceinline__ float ldv(int f32, const void* p, int i) {
    return f32 ? ((const float*)p)[i] : bf(((const u16*)p)[i]);
}
// fma-chain dot (matches the validated selection math from the passing round).
__device__ __forceinline__ float dot3(float x0, float x1, float x2,
                                      float y0, float y1, float y2) {
    return __fmaf_rn(x2, y2, __fmaf_rn(x1, y1, __fmul_rn(x0, y0)));
}
// Monotonic u32 key: ordering on keys == ordering on float distances (incl. negatives).
__device__ __forceinline__ u32 mkey32(float d) {
    u32 f = __float_as_uint(d);
    return f ^ (u32)((((int)f) >> 31) | 0x80000000);
}

// ---- canon: w2b | w1a | w1b as FP32 table (dtype-normalized, full precision) ----
__global__ __launch_bounds__(256) void k_canon(const void* __restrict__ probe,
                                               const void* __restrict__ w2b,
                                               const void* __restrict__ w1a,
                                               const void* __restrict__ w1b,
                                               float* __restrict__ canon) {
    int f32 = detect_f32(probe);
    int ix = blockIdx.x * 256 + threadIdx.x;       // 0..32767
    const void* src; int j;
    if (ix < 16384)      { src = w2b; j = ix; }          // 64x256
    else if (ix < 28672) { src = w1a; j = ix - 16384; }  // 64x192
    else                 { src = w1b; j = ix - 28672; }  // 64x64
    canon[ix] = ldv(f32, src, j);
}

// ---- prep: pcl -> float4 (x,y,z,sumsq) ----
__global__ __launch_bounds__(256) void k_prep(const void* __restrict__ probe,
                                              const void* __restrict__ pcl,
                                              float4* __restrict__ pcl4) {
    int f32 = detect_f32(probe);
    int i = blockIdx.x * 256 + threadIdx.x;        // 0..8191
    float x = ldv(f32, pcl, i*3+0), y = ldv(f32, pcl, i*3+1), z = ldv(f32, pcl, i*3+2);
    float s = __fadd_rn(__fadd_rn(__fmul_rn(x,x), __fmul_rn(y,y)), __fmul_rn(z,z));
    pcl4[i] = make_float4(x, y, z, s);
}

// ---- argmin over M for each noise point; 16 lanes per query; 32 KB chunked tile ----
__global__ __launch_bounds__(256) void k_close(const float4* __restrict__ pcl4,
                                               const void* __restrict__ noise,
                                               u16* __restrict__ cidx) {
    __shared__ __align__(16) float4 tile[2048];
    int f32 = detect_f32(noise);
    int t = threadIdx.x, g = t >> 4, s = t & 15;
    int q = blockIdx.x * 16 + g;                   // global noise-point id
    int b = q >> 13;
    const float4* src = pcl4 + ((size_t)b << 12);
    float x0 = ldv(f32, noise, q*3+0), x1 = ldv(f32, noise, q*3+1), x2 = ldv(f32, noise, q*3+2);
    float sx = __fadd_rn(__fadd_rn(__fmul_rn(x0,x0), __fmul_rn(x1,x1)), __fmul_rn(x2,x2));
    float bd = FLT_MAX; int bi = 0;
    for (int ch = 0; ch < 2; ++ch) {
        __syncthreads();
#pragma unroll
        for (int i = 0; i < 8; ++i) { int ix = t + (i << 8); tile[ix] = src[(ch << 11) + ix]; }
        __syncthreads();
        for (int j = 0; j < 128; ++j) {
            int cl = (j << 4) + s;                 // lane-interleaved: conflict-free LDS
            float4 p = tile[cl];
            float dot = dot3(x0, x1, x2, p.x, p.y, p.z);
            float d = __fadd_rn(__fsub_rn(sx, __fmul_rn(2.0f, dot)), p.w);
            int c = (ch << 11) + cl;               // strictly increasing within thread
            if (d < bd) { bd = d; bi = c; }        // -> first-min on ties
        }
    }
#pragma unroll
    for (int m = 8; m >= 1; m >>= 1) {             // lexicographic (d, idx) merge
        float od = __shfl_xor(bd, m);
        int   oi = __shfl_xor(bi, m);
        if (od < bd || (od == bd && oi < bi)) { bd = od; bi = oi; }
    }
    if (s == 0) cidx[q] = (u16)(bi & 4095);        // masked
}

// ---- k_knnp: per-(query, candidate-quarter) sorted top-16 via REGISTER lists ----
// 2048 blocks = 512 query-groups x 4 quarters; 256 thr = 16 queries x 16 lanes.
// Explicit scalars k0..k15/i0..i15 (no array -> no scratch demotion). Branch-free
// ripple insert under a cheap guard; leader lane 16-way merges group lists.
#define INS(P) { u32 c_ = (v < k##P); u32 nk = c_ ? v : k##P; u32 nv = c_ ? k##P : v; \
                 u32 ni = c_ ? vi : i##P; u32 nj = c_ ? i##P : vi; \
                 k##P = nk; i##P = ni; v = nv; vi = nj; }
__global__ __launch_bounds__(256, 6) void k_knnp(const float4* __restrict__ pcl4,
                                                 u32* __restrict__ pkey,
                                                 u16* __restrict__ pidx) {
    __shared__ u32 skey[4096];                     // 16 KB: 256 lanes x 16 keys
    __shared__ u16 sidx[4096];                     // 8 KB
    int t = threadIdx.x, g = t >> 4, s = t & 15;
    int bx = blockIdx.x;
    int quarter = bx & 3;
    int q = ((bx >> 2) << 4) + g;                  // 0..8191 global clean id
    int b = q >> 12;
    const float4* src = pcl4 + ((size_t)b << 12);
    float4 Q = pcl4[q];
    float x0 = Q.x, x1 = Q.y, x2 = Q.z, sx = Q.w;
    u32 k0=~0u,k1=~0u,k2=~0u,k3=~0u,k4=~0u,k5=~0u,k6=~0u,k7=~0u,
        k8=~0u,k9=~0u,k10=~0u,k11=~0u,k12=~0u,k13=~0u,k14=~0u,k15=~0u;
    u32 i0=0,i1=0,i2=0,i3=0,i4=0,i5=0,i6=0,i7=0,
        i8=0,i9=0,i10=0,i11=0,i12=0,i13=0,i14=0,i15=0;
    int cb = quarter << 10;
    for (int j = 0; j < 64; ++j) {
        int cin = cb + (j << 4) + s;               // in-batch idx, increasing per lane
        float4 p = src[cin];
        float dot = dot3(x0, x1, x2, p.x, p.y, p.z);
        float d = __fadd_rn(__fsub_rn(sx, __fmul_rn(2.0f, dot)), p.w);
        u32 v = mkey32(d);
        u32 vi = (u32)cin;
        if (v < k15) {                             // strict <: equal keeps earlier idx
            INS(0) INS(1) INS(2) INS(3) INS(4) INS(5) INS(6) INS(7)
            INS(8) INS(9) INS(10) INS(11) INS(12) INS(13) INS(14) INS(15)
        }
    }
    int tb = t << 4;
    skey[tb+0]=k0;  skey[tb+1]=k1;  skey[tb+2]=k2;  skey[tb+3]=k3;
    skey[tb+4]=k4;  skey[tb+5]=k5;  skey[tb+6]=k6;  skey[tb+7]=k7;
    skey[tb+8]=k8;  skey[tb+9]=k9;  skey[tb+10]=k10; skey[tb+11]=k11;
    skey[tb+12]=k12; skey[tb+13]=k13; skey[tb+14]=k14; skey[tb+15]=k15;
    sidx[tb+0]=(u16)i0;  sidx[tb+1]=(u16)i1;  sidx[tb+2]=(u16)i2;  sidx[tb+3]=(u16)i3;
    sidx[tb+4]=(u16)i4;  sidx[tb+5]=(u16)i5;  sidx[tb+6]=(u16)i6;  sidx[tb+7]=(u16)i7;
    sidx[tb+8]=(u16)i8;  sidx[tb+9]=(u16)i9;  sidx[tb+10]=(u16)i10; sidx[tb+11]=(u16)i11;
    sidx[tb+12]=(u16)i12; sidx[tb+13]=(u16)i13; sidx[tb+14]=(u16)i14; sidx[tb+15]=(u16)i15;
    __syncthreads();
    if (s == 0) {                                  // leader: 16-way merge of sorted lists
        int heads[16];
#pragma unroll
        for (int p = 0; p < 16; ++p) heads[p] = 0;
        int base = g << 4;
        size_t ob = ((size_t)q << 6) + (quarter << 4);
        for (int o = 0; o < 16; ++o) {
            u32 bk = 0xFFFFFFFFu, bi = 0xFFFFFFFFu; int bt = 0;
#pragma unroll
            for (int tt = 0; tt < 16; ++tt) {
                int hp = heads[tt];
                if (hp < 16) {
                    u32 kv = skey[((base + tt) << 4) + hp];
                    u32 iv = sidx[((base + tt) << 4) + hp];
                    if (kv < bk || (kv == bk && iv < bi)) { bk = kv; bi = iv; bt = tt; }
                }
            }
#pragma unroll
            for (int tt = 0; tt < 16; ++tt) if (tt == bt) heads[tt]++;
            pkey[ob + o] = bk; pidx[ob + o] = (u16)bi;
        }
    }
}

// ---- k_kmerge: per query, rank-merge 4 sorted 16-lists -> final top-16 idx ----
__global__ __launch_bounds__(256) void k_kmerge(const u32* __restrict__ pkey,
                                                const u16* __restrict__ pidx,
                                                u16* __restrict__ knn) {
    __shared__ u32 mk[1024];                       // 16 q x 64 entries
    __shared__ u16 mi[1024];
    int t = threadIdx.x, g = t >> 4, s = t & 15;
    int q = blockIdx.x * 16 + g;
    size_t qb = (size_t)q << 6;
    u32 ke[4]; u32 ie[4];
#pragma unroll
    for (int r = 0; r < 4; ++r) {
        int e = s + (r << 4);
        u32 kv = pkey[qb + e]; u16 iv = pidx[qb + e];
        mk[(g << 6) + e] = kv; mi[(g << 6) + e] = iv;
        ke[r] = kv; ie[r] = (u32)iv;
    }
    __syncthreads();
    int rank[4] = {0, 0, 0, 0};
    for (int j = 0; j < 64; ++j) {
        u32 kj = mk[(g << 6) + j];
        u32 ij = (u32)mi[(g << 6) + j];
#pragma unroll
        for (int r = 0; r < 4; ++r)
            rank[r] += (kj < ke[r]) || (kj == ke[r] && ij < ie[r]);  // lex (key, idx)
    }
#pragma unroll
    for (int r = 0; r < 4; ++r)
        if (rank[r] < 16) knn[((size_t)q << 4) + rank[r]] = (u16)ie[r];
}

// ---- fused tail: weights, deltas, MLP_CONV2 (k-contracted), df, MLP_CONV_1d ----
__global__ __launch_bounds__(256) void k_tail(const float4* __restrict__ pcl4,
                                              const void* __restrict__ noise,
                                              const void* __restrict__ feat,
                                              const u16* __restrict__ cidx,
                                              const u16* __restrict__ knn,
                                              const void* __restrict__ w2a,
                                              const void* __restrict__ b2a,
                                              const void* __restrict__ g2a,
                                              const void* __restrict__ bt2a,
                                              const float* __restrict__ canon,
                                              const void* __restrict__ b2b,
                                              const void* __restrict__ b1a,
                                              const void* __restrict__ g1a,
                                              const void* __restrict__ bt1a,
                                              const void* __restrict__ b1b,
                                              void* __restrict__ outp) {
    __shared__ float w2at[6][256];                 // transposed: conflict-free reads
    __shared__ float sc2[256], of2[256];
    __shared__ float b2bf[64], s1[64], o1[64], b1f[64];
    __shared__ __align__(16) float hb[4][256];     // per-wave hbar = sum_k w_k * h_k
    __shared__ __align__(16) float dfs[4][192];    // per-wave df row
    __shared__ __align__(16) float h1s[4][64];
    __shared__ float dpb[4][16][6];
    __shared__ float wbuf[4][16];
    __shared__ int   jbuf[4][16];

    int f32 = detect_f32(noise);
    int t = threadIdx.x;
    {   // stage weights + fold BN (z = dot*sc + (b*sc + bt))
        float s2 = ldv(f32, g2a, t) / sqrtf(1.0f + 1e-5f);
        sc2[t] = s2;
        of2[t] = ldv(f32, b2a, t) * s2 + ldv(f32, bt2a, t);
#pragma unroll
        for (int c = 0; c < 6; ++c) w2at[c][t] = ldv(f32, w2a, t*6+c);
        if (t < 64) {
            b2bf[t] = ldv(f32, b2b, t);
            float s = ldv(f32, g1a, t) / sqrtf(1.0f + 1e-5f);
            s1[t] = s; o1[t] = ldv(f32, b1a, t) * s + ldv(f32, bt1a, t); b1f[t] = ldv(f32, b1b, t);
        }
    }
    int lane = t & 63, wv = t >> 6;
    int q = blockIdx.x * 4 + wv;                   // one wave per noise point
    int b = q >> 13;
    int pbase = (b << 12);
    int ci = ((int)cidx[q]) & 4095;
    float4 cp = pcl4[pbase + ci];
    float x0 = ldv(f32, noise, q*3+0), x1 = ldv(f32, noise, q*3+1), x2 = ldv(f32, noise, q*3+2);
    float e = 0.0f;
    if (lane >= 1 && lane < 16) {                  // lane k handles neighbor rank k (drop rank 0)
        int jk = ((int)knn[(size_t)(pbase + ci) * 16 + lane]) & 4095;
        float4 p = pcl4[pbase + jk];
        float d0 = p.x - x0, d1 = p.y - x1, d2 = p.z - x2;
        float dst = sqrtf(__fadd_rn(__fadd_rn(__fmul_rn(d0,d0), __fmul_rn(d1,d1)), __fmul_rn(d2,d2)));
        e = expf(-10.0f * dst);
        dpb[wv][lane][0] = d0; dpb[wv][lane][1] = d1; dpb[wv][lane][2] = d2;
        dpb[wv][lane][3] = cp.x; dpb[wv][lane][4] = cp.y; dpb[wv][lane][5] = cp.z;
        jbuf[wv][lane] = jk;
    }
    float es = e;
#pragma unroll
    for (int m = 32; m >= 1; m >>= 1) es += __shfl_xor(es, m);
    float den = es + 1e-7f;
    if (lane >= 1 && lane < 16) wbuf[wv][lane] = e / den;
    float wsum = es / den;                         // sum_k w_k (for b2b term)
    __syncthreads();

    // close_feat + co_feature (lane = channel)
    size_t fcb = ((size_t)(pbase + ci)) << 6;
    float cf, co = 0.0f;
    if (f32) {
        const float* ff = (const float*)feat;
        cf = ff[fcb + lane];
#pragma unroll
        for (int k = 1; k < 16; ++k)
            co += wbuf[wv][k] * ff[(((size_t)(pbase + jbuf[wv][k])) << 6) + lane];
    } else {
        const u16* fb = (const u16*)feat;
        cf = bf(fb[fcb + lane]);
#pragma unroll
        for (int k = 1; k < 16; ++k)
            co += wbuf[wv][k] * bf(fb[(((size_t)(pbase + jbuf[wv][k])) << 6) + lane]);
    }

    // layer1: hbar[ch] = sum_k w_k * relu(bn(dp·w2a[ch])); 4 channels per lane
    float wa[4][6], scr[4], ofr[4];
#pragma unroll
    for (int r = 0; r < 4; ++r) {
        int ch = lane + (r << 6);
#pragma unroll
        for (int c = 0; c < 6; ++c) wa[r][c] = w2at[c][ch];
        scr[r] = sc2[ch]; ofr[r] = of2[ch];
    }
    float hv[4] = {0.0f, 0.0f, 0.0f, 0.0f};
#pragma unroll
    for (int k = 1; k < 16; ++k) {
        float p0 = dpb[wv][k][0], p1 = dpb[wv][k][1], p2 = dpb[wv][k][2];
        float p3 = dpb[wv][k][3], p4 = dpb[wv][k][4], p5 = dpb[wv][k][5];
        float wk = wbuf[wv][k];
#pragma unroll
        for (int r = 0; r < 4; ++r) {
            float z = p0*wa[r][0] + p1*wa[r][1] + p2*wa[r][2]
                    + p3*wa[r][3] + p4*wa[r][4] + p5*wa[r][5];
            z = z * scr[r] + ofr[r];
            z = fmaxf(z, 0.0f);
            hv[r] += wk * z;
        }
    }
#pragma unroll
    for (int r = 0; r < 4; ++r) hb[wv][lane + (r << 6)] = hv[r];
    __syncthreads();

    // layer2 (k-contracted): pf[o] = b2b[o]*wsum + sum_c hbar[c]*w2b[o][c]
    float acc = b2bf[lane] * wsum;
    {
        const float4* wrow = reinterpret_cast<const float4*>(canon + (lane << 8));
        const float4* hrow = reinterpret_cast<const float4*>(&hb[wv][0]);
#pragma unroll
        for (int i = 0; i < 64; ++i) {
            float4 w = wrow[i], h = hrow[i];
            acc += w.x*h.x + w.y*h.y + w.z*h.z + w.w*h.w;
        }
    }
    dfs[wv][lane]       = cf;                      // df = [close_feat | co_feature | point_feature]
    dfs[wv][64 + lane]  = co;
    dfs[wv][128 + lane] = acc;
    __syncthreads();

    // MLP_CONV_1d layer 1: 192 -> 64, BN+ReLU (fp32 weights from canon)
    float acc1 = 0.0f;
    {
        const float4* wr = reinterpret_cast<const float4*>(canon + 16384 + lane * 192);
        const float4* dv = reinterpret_cast<const float4*>(&dfs[wv][0]);
#pragma unroll
        for (int i = 0; i < 48; ++i) {
            float4 w = wr[i], a = dv[i];
            acc1 += w.x*a.x + w.y*a.y + w.z*a.z + w.w*a.w;
        }
    }
    float z1 = acc1 * s1[lane] + o1[lane];
    z1 = fmaxf(z1, 0.0f);
    h1s[wv][lane] = z1;
    __syncthreads();

    // MLP_CONV_1d layer 2: 64 -> 64; output dtype = detected input dtype
    float a2 = b1f[lane];
    {
        const float4* wr2 = reinterpret_cast<const float4*>(canon + 28672 + (lane << 6));
        const float4* hv2 = reinterpret_cast<const float4*>(&h1s[wv][0]);
#pragma unroll
        for (int i = 0; i < 16; ++i) {
            float4 w = wr2[i], a = hv2[i];
            a2 += w.x*a.x + w.y*a.y + w.z*a.z + w.w*a.w;
        }
    }
    size_t ob = ((size_t)q << 6) + lane;
    if (f32) ((float*)outp)[ob] = a2;
    else     ((u16*)outp)[ob]   = f2bf(a2);
}

extern "C" void kernel_launch(void* const* d_in, const int* in_sizes, int n_in,
                              void* d_out, int out_size, void* d_ws, size_t ws_size,
                              hipStream_t stream) {
    const void* pcl   = d_in[0];
    const void* noise = d_in[1];
    const void* feat  = d_in[2];
    const void* w2a   = d_in[3];
    const void* b2a   = d_in[4];
    const void* g2a   = d_in[5];
    const void* bt2a  = d_in[6];
    const void* w2b   = d_in[7];
    const void* b2b   = d_in[8];
    const void* w1a   = d_in[9];
    const void* b1a   = d_in[10];
    const void* g1a   = d_in[11];
    const void* bt1a  = d_in[12];
    const void* w1b   = d_in[13];
    const void* b1b   = d_in[14];

    char* ws = (char*)d_ws;
    float4* pcl4 = (float4*)ws;                    // 128 KB: [B,M] x (x,y,z,sumsq)
    u16* cidx = (u16*)(ws + 131072);               // 32 KB: [B,N]
    u16* knn  = (u16*)(ws + 163840);               // 256 KB: [B,M,16]
    float* canon = (float*)(ws + 425984);          // 128 KB: fp32 w2b|w1a|w1b
    u32* pkey = (u32*)(ws + 557056);               // 2 MB: [B*M][4][16] keys
    u16* pidx = (u16*)(ws + 2654208);              // 1 MB: [B*M][4][16] idx
    // total workspace: ~3.7 MB

    k_canon <<<128,  256, 0, stream>>>(noise, w2b, w1a, w1b, canon);
    k_prep  <<<32,   256, 0, stream>>>(noise, pcl, pcl4);
    k_close <<<1024, 256, 0, stream>>>(pcl4, noise, cidx);
    k_knnp  <<<2048, 256, 0, stream>>>(pcl4, pkey, pidx);
    k_kmerge<<<512,  256, 0, stream>>>(pkey, pidx, knn);
    k_tail  <<<4096, 256, 0, stream>>>(pcl4, noise, feat, cidx, knn,
                                       w2a, b2a, g2a, bt2a, canon, b2b,
                                       b1a, g1a, bt1a, b1b, d_out);
}

// Round 9
// 374.381 us; speedup vs baseline: 1.6403x; 1.3433x over previous
//
#include <hip/hip_runtime.h>
#include <float.h>

typedef unsigned short u16;
typedef unsigned int u32;

// B=2, N=8192, M=4096, C=64, K=16, HID=256
__device__ __forceinline__ float bf(u16 u) { return __uint_as_float(((u32)u) << 16); }
__device__ __forceinline__ u16 f2bf(float v) {
    u32 x = __float_as_uint(v);
    u32 r = x + 0x7fffu + ((x >> 16) & 1u);
    return (u16)(r >> 16);
}
// Dtype probe on EVEN u16 positions of a large ~N(0,1) buffer (pcl_noise).
__device__ __forceinline__ int detect_f32(const void* probe) {
    const u16* u = (const u16*)probe;
    u16 v = u[(threadIdx.x & 63) * 2];
    int e = (int)((v >> 7) & 0xFF);
    int moderate = (e >= 100) && (e <= 140);
    return __popcll(__ballot(moderate)) < 48;   // few moderate -> fp32
}
__device__ __forceinline__ float ldv(int f32, const void* p, int i) {
    return f32 ? ((const float*)p)[i] : bf(((const u16*)p)[i]);
}
// fma-chain dot (matches the validated selection math from the passing rounds).
__device__ __forceinline__ float dot3(float x0, float x1, float x2,
                                      float y0, float y1, float y2) {
    return __fmaf_rn(x2, y2, __fmaf_rn(x1, y1, __fmul_rn(x0, y0)));
}
// Monotonic u32 key: ordering on keys == ordering on float distances.
__device__ __forceinline__ u32 mkey32(float d) {
    u32 f = __float_as_uint(d);
    return f ^ (u32)((((int)f) >> 31) | 0x80000000);
}

// ---- canon: w2b | w1a | w1b as FP32 table (dtype-normalized, full precision) ----
__global__ __launch_bounds__(256) void k_canon(const void* __restrict__ probe,
                                               const void* __restrict__ w2b,
                                               const void* __restrict__ w1a,
                                               const void* __restrict__ w1b,
                                               float* __restrict__ canon) {
    int f32 = detect_f32(probe);
    int ix = blockIdx.x * 256 + threadIdx.x;       // 0..32767
    const void* src; int j;
    if (ix < 16384)      { src = w2b; j = ix; }          // 64x256
    else if (ix < 28672) { src = w1a; j = ix - 16384; }  // 64x192
    else                 { src = w1b; j = ix - 28672; }  // 64x64
    canon[ix] = ldv(f32, src, j);
}

// ---- prep: pcl -> float4 (x,y,z,sumsq) ----
__global__ __launch_bounds__(256) void k_prep(const void* __restrict__ probe,
                                              const void* __restrict__ pcl,
                                              float4* __restrict__ pcl4) {
    int f32 = detect_f32(probe);
    int i = blockIdx.x * 256 + threadIdx.x;        // 0..8191
    float x = ldv(f32, pcl, i*3+0), y = ldv(f32, pcl, i*3+1), z = ldv(f32, pcl, i*3+2);
    float s = __fadd_rn(__fadd_rn(__fmul_rn(x,x), __fmul_rn(y,y)), __fmul_rn(z,z));
    pcl4[i] = make_float4(x, y, z, s);
}

// ---- argmin over M for each noise point; 16 lanes per query; 32 KB chunked tile ----
__global__ __launch_bounds__(256) void k_close(const float4* __restrict__ pcl4,
                                               const void* __restrict__ noise,
                                               u16* __restrict__ cidx) {
    __shared__ __align__(16) float4 tile[2048];
    int f32 = detect_f32(noise);
    int t = threadIdx.x, g = t >> 4, s = t & 15;
    int q = blockIdx.x * 16 + g;                   // global noise-point id
    int b = q >> 13;
    const float4* src = pcl4 + ((size_t)b << 12);
    float x0 = ldv(f32, noise, q*3+0), x1 = ldv(f32, noise, q*3+1), x2 = ldv(f32, noise, q*3+2);
    float sx = __fadd_rn(__fadd_rn(__fmul_rn(x0,x0), __fmul_rn(x1,x1)), __fmul_rn(x2,x2));
    float bd = FLT_MAX; int bi = 0;
    for (int ch = 0; ch < 2; ++ch) {
        __syncthreads();
#pragma unroll
        for (int i = 0; i < 8; ++i) { int ix = t + (i << 8); tile[ix] = src[(ch << 11) + ix]; }
        __syncthreads();
        for (int j = 0; j < 128; ++j) {
            int cl = (j << 4) + s;                 // lane-interleaved: conflict-free LDS
            float4 p = tile[cl];
            float dot = dot3(x0, x1, x2, p.x, p.y, p.z);
            float d = __fadd_rn(__fsub_rn(sx, __fmul_rn(2.0f, dot)), p.w);
            int c = (ch << 11) + cl;               // strictly increasing within thread
            if (d < bd) { bd = d; bi = c; }        // -> first-min on ties
        }
    }
#pragma unroll
    for (int m = 8; m >= 1; m >>= 1) {             // lexicographic (d, idx) merge
        float od = __shfl_xor(bd, m);
        int   oi = __shfl_xor(bi, m);
        if (od < bd || (od == bd && oi < bi)) { bd = od; bi = oi; }
    }
    if (s == 0) cidx[q] = (u16)(bi & 4095);        // masked
}

// ---- k_knnp: per-(query, candidate-quarter) sorted top-16 via REGISTER lists ----
#define INS(P) { u32 c_ = (v < k##P); u32 nk = c_ ? v : k##P; u32 nv = c_ ? k##P : v; \
                 u32 ni = c_ ? vi : i##P; u32 nj = c_ ? i##P : vi; \
                 k##P = nk; i##P = ni; v = nv; vi = nj; }
__global__ __launch_bounds__(256, 6) void k_knnp(const float4* __restrict__ pcl4,
                                                 u32* __restrict__ pkey,
                                                 u16* __restrict__ pidx) {
    __shared__ u32 skey[4096];                     // 16 KB: 256 lanes x 16 keys
    __shared__ u16 sidx[4096];                     // 8 KB
    int t = threadIdx.x, g = t >> 4, s = t & 15;
    int bx = blockIdx.x;
    int quarter = bx & 3;
    int q = ((bx >> 2) << 4) + g;                  // 0..8191 global clean id
    int b = q >> 12;
    const float4* src = pcl4 + ((size_t)b << 12);
    float4 Q = pcl4[q];
    float x0 = Q.x, x1 = Q.y, x2 = Q.z, sx = Q.w;
    u32 k0=~0u,k1=~0u,k2=~0u,k3=~0u,k4=~0u,k5=~0u,k6=~0u,k7=~0u,
        k8=~0u,k9=~0u,k10=~0u,k11=~0u,k12=~0u,k13=~0u,k14=~0u,k15=~0u;
    u32 i0=0,i1=0,i2=0,i3=0,i4=0,i5=0,i6=0,i7=0,
        i8=0,i9=0,i10=0,i11=0,i12=0,i13=0,i14=0,i15=0;
    int cb = quarter << 10;
    for (int j = 0; j < 64; ++j) {
        int cin = cb + (j << 4) + s;               // in-batch idx, increasing per lane
        float4 p = src[cin];
        float dot = dot3(x0, x1, x2, p.x, p.y, p.z);
        float d = __fadd_rn(__fsub_rn(sx, __fmul_rn(2.0f, dot)), p.w);
        u32 v = mkey32(d);
        u32 vi = (u32)cin;
        if (v < k15) {                             // strict <: equal keeps earlier idx
            INS(0) INS(1) INS(2) INS(3) INS(4) INS(5) INS(6) INS(7)
            INS(8) INS(9) INS(10) INS(11) INS(12) INS(13) INS(14) INS(15)
        }
    }
    int tb = t << 4;
    skey[tb+0]=k0;  skey[tb+1]=k1;  skey[tb+2]=k2;  skey[tb+3]=k3;
    skey[tb+4]=k4;  skey[tb+5]=k5;  skey[tb+6]=k6;  skey[tb+7]=k7;
    skey[tb+8]=k8;  skey[tb+9]=k9;  skey[tb+10]=k10; skey[tb+11]=k11;
    skey[tb+12]=k12; skey[tb+13]=k13; skey[tb+14]=k14; skey[tb+15]=k15;
    sidx[tb+0]=(u16)i0;  sidx[tb+1]=(u16)i1;  sidx[tb+2]=(u16)i2;  sidx[tb+3]=(u16)i3;
    sidx[tb+4]=(u16)i4;  sidx[tb+5]=(u16)i5;  sidx[tb+6]=(u16)i6;  sidx[tb+7]=(u16)i7;
    sidx[tb+8]=(u16)i8;  sidx[tb+9]=(u16)i9;  sidx[tb+10]=(u16)i10; sidx[tb+11]=(u16)i11;
    sidx[tb+12]=(u16)i12; sidx[tb+13]=(u16)i13; sidx[tb+14]=(u16)i14; sidx[tb+15]=(u16)i15;
    __syncthreads();
    if (s == 0) {                                  // leader: 16-way merge of sorted lists
        int heads[16];
#pragma unroll
        for (int p = 0; p < 16; ++p) heads[p] = 0;
        int base = g << 4;
        size_t ob = ((size_t)q << 6) + (quarter << 4);
        for (int o = 0; o < 16; ++o) {
            u32 bk = 0xFFFFFFFFu, bi = 0xFFFFFFFFu; int bt = 0;
#pragma unroll
            for (int tt = 0; tt < 16; ++tt) {
                int hp = heads[tt];
                if (hp < 16) {
                    u32 kv = skey[((base + tt) << 4) + hp];
                    u32 iv = sidx[((base + tt) << 4) + hp];
                    if (kv < bk || (kv == bk && iv < bi)) { bk = kv; bi = iv; bt = tt; }
                }
            }
#pragma unroll
            for (int tt = 0; tt < 16; ++tt) if (tt == bt) heads[tt]++;
            pkey[ob + o] = bk; pidx[ob + o] = (u16)bi;
        }
    }
}

// ---- k_kmerge: per query, rank-merge 4 sorted 16-lists -> final top-16 idx ----
__global__ __launch_bounds__(256) void k_kmerge(const u32* __restrict__ pkey,
                                                const u16* __restrict__ pidx,
                                                u16* __restrict__ knn) {
    __shared__ u32 mk[1024];                       // 16 q x 64 entries
    __shared__ u16 mi[1024];
    int t = threadIdx.x, g = t >> 4, s = t & 15;
    int q = blockIdx.x * 16 + g;
    size_t qb = (size_t)q << 6;
    u32 ke[4]; u32 ie[4];
#pragma unroll
    for (int r = 0; r < 4; ++r) {
        int e = s + (r << 4);
        u32 kv = pkey[qb + e]; u16 iv = pidx[qb + e];
        mk[(g << 6) + e] = kv; mi[(g << 6) + e] = iv;
        ke[r] = kv; ie[r] = (u32)iv;
    }
    __syncthreads();
    int rank[4] = {0, 0, 0, 0};
    for (int j = 0; j < 64; ++j) {
        u32 kj = mk[(g << 6) + j];
        u32 ij = (u32)mi[(g << 6) + j];
#pragma unroll
        for (int r = 0; r < 4; ++r)
            rank[r] += (kj < ke[r]) || (kj == ke[r] && ij < ie[r]);  // lex (key, idx)
    }
#pragma unroll
    for (int r = 0; r < 4; ++r)
        if (rank[r] < 16) knn[((size_t)q << 4) + rank[r]] = (u16)ie[r];
}

// ---- fused tail: 4 queries per wave (weight-load amortization), 16 per block ----
// Per-query arithmetic bit-identical to the validated single-query version;
// weight float4 loads from canon now feed 4 accumulator chains each.
__global__ __launch_bounds__(256) void k_tail(const float4* __restrict__ pcl4,
                                              const void* __restrict__ noise,
                                              const void* __restrict__ feat,
                                              const u16* __restrict__ cidx,
                                              const u16* __restrict__ knn,
                                              const void* __restrict__ w2a,
                                              const void* __restrict__ b2a,
                                              const void* __restrict__ g2a,
                                              const void* __restrict__ bt2a,
                                              const float* __restrict__ canon,
                                              const void* __restrict__ b2b,
                                              const void* __restrict__ b1a,
                                              const void* __restrict__ g1a,
                                              const void* __restrict__ bt1a,
                                              const void* __restrict__ b1b,
                                              void* __restrict__ outp) {
    __shared__ float w2at[6][256];                 // 6 KB
    __shared__ float sc2[256], of2[256];           // 2 KB
    __shared__ float b2bf[64], s1[64], o1[64], b1f[64]; // 1 KB
    __shared__ __align__(16) float hb[4][4][256];  // 16 KB: [wave][ql][ch]
    __shared__ __align__(16) float dfs[4][4][192]; // 12 KB
    __shared__ __align__(16) float h1s[4][4][64];  // 4 KB
    __shared__ float dpb[4][4][16][6];             // 6 KB
    __shared__ float wbuf[4][4][16];               // 1 KB
    __shared__ int   jbuf[4][4][16];               // 1 KB
    __shared__ float wsb[4][4];                    // wsum per (wave, ql)

    int f32 = detect_f32(noise);
    int t = threadIdx.x;
    {   // stage weights + fold BN (z = dot*sc + (b*sc + bt))
        float s2 = ldv(f32, g2a, t) / sqrtf(1.0f + 1e-5f);
        sc2[t] = s2;
        of2[t] = ldv(f32, b2a, t) * s2 + ldv(f32, bt2a, t);
#pragma unroll
        for (int c = 0; c < 6; ++c) w2at[c][t] = ldv(f32, w2a, t*6+c);
        if (t < 64) {
            b2bf[t] = ldv(f32, b2b, t);
            float s = ldv(f32, g1a, t) / sqrtf(1.0f + 1e-5f);
            s1[t] = s; o1[t] = ldv(f32, b1a, t) * s + ldv(f32, bt1a, t); b1f[t] = ldv(f32, b1b, t);
        }
    }
    int lane = t & 63, wv = t >> 6;
    int qbase = blockIdx.x * 16 + wv * 4;          // 4 queries per wave
    // ---- front-end: lane group ql=lane>>4 handles query qbase+ql, s=lane&15 = rank ----
    {
        int ql = lane >> 4, s = lane & 15;
        int q = qbase + ql;
        int b = q >> 13;
        int pbase = (b << 12);
        int ci = ((int)cidx[q]) & 4095;
        float4 cp = pcl4[pbase + ci];
        float x0 = ldv(f32, noise, q*3+0), x1 = ldv(f32, noise, q*3+1), x2 = ldv(f32, noise, q*3+2);
        float e = 0.0f;
        if (s >= 1) {                              // rank 1..15 (drop rank 0 = self)
            int jk = ((int)knn[(size_t)(pbase + ci) * 16 + s]) & 4095;
            float4 p = pcl4[pbase + jk];
            float d0 = p.x - x0, d1 = p.y - x1, d2 = p.z - x2;
            float dst = sqrtf(__fadd_rn(__fadd_rn(__fmul_rn(d0,d0), __fmul_rn(d1,d1)), __fmul_rn(d2,d2)));
            e = expf(-10.0f * dst);
            dpb[wv][ql][s][0] = d0; dpb[wv][ql][s][1] = d1; dpb[wv][ql][s][2] = d2;
            dpb[wv][ql][s][3] = cp.x; dpb[wv][ql][s][4] = cp.y; dpb[wv][ql][s][5] = cp.z;
            jbuf[wv][ql][s] = jk;
        }
        float es = e;
#pragma unroll
        for (int m = 8; m >= 1; m >>= 1) es += __shfl_xor(es, m, 16);  // within 16-lane group
        float den = es + 1e-7f;
        if (s >= 1) wbuf[wv][ql][s] = e / den;
        if (s == 0) wsb[wv][ql] = es / den;        // sum_k w_k
    }
    __syncthreads();

    // ---- close_feat + co_feature: lane = channel, loop over the wave's 4 queries ----
    float cf[4], co[4];
#pragma unroll
    for (int ql = 0; ql < 4; ++ql) {
        int q = qbase + ql;
        int b = q >> 13;
        int pbase = (b << 12);
        int ci = ((int)cidx[q]) & 4095;
        size_t fcb = ((size_t)(pbase + ci)) << 6;
        float c0, c1 = 0.0f;
        if (f32) {
            const float* ff = (const float*)feat;
            c0 = ff[fcb + lane];
#pragma unroll
            for (int k = 1; k < 16; ++k)
                c1 += wbuf[wv][ql][k] * ff[(((size_t)(pbase + jbuf[wv][ql][k])) << 6) + lane];
        } else {
            const u16* fb = (const u16*)feat;
            c0 = bf(fb[fcb + lane]);
#pragma unroll
            for (int k = 1; k < 16; ++k)
                c1 += wbuf[wv][ql][k] * bf(fb[(((size_t)(pbase + jbuf[wv][ql][k])) << 6) + lane]);
        }
        cf[ql] = c0; co[ql] = c1;
    }

    // ---- layer1: hbar[ch] = sum_k w_k * relu(bn(dp·w2a[ch])); 4 ch x 4 queries / lane ----
    float wa[4][6], scr[4], ofr[4];
#pragma unroll
    for (int r = 0; r < 4; ++r) {
        int ch = lane + (r << 6);
#pragma unroll
        for (int c = 0; c < 6; ++c) wa[r][c] = w2at[c][ch];
        scr[r] = sc2[ch]; ofr[r] = of2[ch];
    }
    float hv[4][4];                                // [ql][r]
#pragma unroll
    for (int ql = 0; ql < 4; ++ql)
#pragma unroll
        for (int r = 0; r < 4; ++r) hv[ql][r] = 0.0f;
#pragma unroll
    for (int k = 1; k < 16; ++k) {
#pragma unroll
        for (int ql = 0; ql < 4; ++ql) {
            float p0 = dpb[wv][ql][k][0], p1 = dpb[wv][ql][k][1], p2 = dpb[wv][ql][k][2];
            float p3 = dpb[wv][ql][k][3], p4 = dpb[wv][ql][k][4], p5 = dpb[wv][ql][k][5];
            float wk = wbuf[wv][ql][k];
#pragma unroll
            for (int r = 0; r < 4; ++r) {
                float z = p0*wa[r][0] + p1*wa[r][1] + p2*wa[r][2]
                        + p3*wa[r][3] + p4*wa[r][4] + p5*wa[r][5];
                z = z * scr[r] + ofr[r];
                z = fmaxf(z, 0.0f);
                hv[ql][r] += wk * z;
            }
        }
    }
#pragma unroll
    for (int ql = 0; ql < 4; ++ql)
#pragma unroll
        for (int r = 0; r < 4; ++r) hb[wv][ql][lane + (r << 6)] = hv[ql][r];
    __syncthreads();

    // ---- layer2 (k-contracted): pf[o] = b2b[o]*wsum + sum_c hbar[c]*w2b[o][c] ----
    // ONE weight float4 load feeds 4 query accumulators (4x traffic amortization).
    float acc[4];
#pragma unroll
    for (int ql = 0; ql < 4; ++ql) acc[ql] = b2bf[lane] * wsb[wv][ql];
    {
        const float4* wrow = reinterpret_cast<const float4*>(canon + (lane << 8));
#pragma unroll 4
        for (int i = 0; i < 64; ++i) {
            float4 w = wrow[i];
#pragma unroll
            for (int ql = 0; ql < 4; ++ql) {
                const float4* hrow = reinterpret_cast<const float4*>(&hb[wv][ql][0]);
                float4 h = hrow[i];
                acc[ql] += w.x*h.x + w.y*h.y + w.z*h.z + w.w*h.w;
            }
        }
    }
#pragma unroll
    for (int ql = 0; ql < 4; ++ql) {
        dfs[wv][ql][lane]       = cf[ql];          // df = [close_feat | co_feature | point_feature]
        dfs[wv][ql][64 + lane]  = co[ql];
        dfs[wv][ql][128 + lane] = acc[ql];
    }
    __syncthreads();

    // ---- MLP_CONV_1d layer 1: 192 -> 64, BN+ReLU ----
    float acc1[4] = {0.0f, 0.0f, 0.0f, 0.0f};
    {
        const float4* wr = reinterpret_cast<const float4*>(canon + 16384 + lane * 192);
#pragma unroll 4
        for (int i = 0; i < 48; ++i) {
            float4 w = wr[i];
#pragma unroll
            for (int ql = 0; ql < 4; ++ql) {
                const float4* dv = reinterpret_cast<const float4*>(&dfs[wv][ql][0]);
                float4 a = dv[i];
                acc1[ql] += w.x*a.x + w.y*a.y + w.z*a.z + w.w*a.w;
            }
        }
    }
#pragma unroll
    for (int ql = 0; ql < 4; ++ql) {
        float z1 = acc1[ql] * s1[lane] + o1[lane];
        z1 = fmaxf(z1, 0.0f);
        h1s[wv][ql][lane] = z1;
    }
    __syncthreads();

    // ---- MLP_CONV_1d layer 2: 64 -> 64; output dtype = detected input dtype ----
    float a2[4];
#pragma unroll
    for (int ql = 0; ql < 4; ++ql) a2[ql] = b1f[lane];
    {
        const float4* wr2 = reinterpret_cast<const float4*>(canon + 28672 + (lane << 6));
#pragma unroll
        for (int i = 0; i < 16; ++i) {
            float4 w = wr2[i];
#pragma unroll
            for (int ql = 0; ql < 4; ++ql) {
                const float4* hv2 = reinterpret_cast<const float4*>(&h1s[wv][ql][0]);
                float4 a = hv2[i];
                a2[ql] += w.x*a.x + w.y*a.y + w.z*a.z + w.w*a.w;
            }
        }
    }
#pragma unroll
    for (int ql = 0; ql < 4; ++ql) {
        size_t ob = ((size_t)(qbase + ql) << 6) + lane;
        if (f32) ((float*)outp)[ob] = a2[ql];
        else     ((u16*)outp)[ob]   = f2bf(a2[ql]);
    }
}

extern "C" void kernel_launch(void* const* d_in, const int* in_sizes, int n_in,
                              void* d_out, int out_size, void* d_ws, size_t ws_size,
                              hipStream_t stream) {
    const void* pcl   = d_in[0];
    const void* noise = d_in[1];
    const void* feat  = d_in[2];
    const void* w2a   = d_in[3];
    const void* b2a   = d_in[4];
    const void* g2a   = d_in[5];
    const void* bt2a  = d_in[6];
    const void* w2b   = d_in[7];
    const void* b2b   = d_in[8];
    const void* w1a   = d_in[9];
    const void* b1a   = d_in[10];
    const void* g1a   = d_in[11];
    const void* bt1a  = d_in[12];
    const void* w1b   = d_in[13];
    const void* b1b   = d_in[14];

    char* ws = (char*)d_ws;
    float4* pcl4 = (float4*)ws;                    // 128 KB: [B,M] x (x,y,z,sumsq)
    u16* cidx = (u16*)(ws + 131072);               // 32 KB: [B,N]
    u16* knn  = (u16*)(ws + 163840);               // 256 KB: [B,M,16]
    float* canon = (float*)(ws + 425984);          // 128 KB: fp32 w2b|w1a|w1b
    u32* pkey = (u32*)(ws + 557056);               // 2 MB: [B*M][4][16] keys
    u16* pidx = (u16*)(ws + 2654208);              // 1 MB: [B*M][4][16] idx
    // total workspace: ~3.7 MB

    k_canon <<<128,  256, 0, stream>>>(noise, w2b, w1a, w1b, canon);
    k_prep  <<<32,   256, 0, stream>>>(noise, pcl, pcl4);
    k_close <<<1024, 256, 0, stream>>>(pcl4, noise, cidx);
    k_knnp  <<<2048, 256, 0, stream>>>(pcl4, pkey, pidx);
    k_kmerge<<<512,  256, 0, stream>>>(pkey, pidx, knn);
    k_tail  <<<1024, 256, 0, stream>>>(pcl4, noise, feat, cidx, knn,
                                       w2a, b2a, g2a, bt2a, canon, b2b,
                                       b1a, g1a, bt1a, b1b, d_out);
}